// Round 8
// baseline (160.096 us; speedup 1.0000x reference)
//
#include <hip/hip_runtime.h>
#include <hip/hip_bf16.h>

// AdaDConv: B=8, C=256, H=W=128, K=3, S=2 -> oh=ow=64, k2=9
//   prep   : fold BN into conv weights -> wt[c][3][28] chunks (10 blocks);
//            bias[16]; gap=0
//   conv   : x -> wlogp[z] partials + fused gap sums. 4-row tile/block
//            (proven round-4 FMA:stall ratio), 32 ch/block (8/wave),
//            weights staged in LDS. Left taps via scalar loads, NOT shfl:
//            keeps lgkmcnt exclusively for weight ds_reads (round-6's
//            shfl chain serialized the FMA pipeline -> 21% VALUBusy).
//   reduce : wlog = sum_z wlogp[z] + bias   (+ chnet in blocks 384..391)
//   final  : column-pair float4 loads; wlog in regs; softmax * reflect -> out

#define EPS 1e-5f
#define CH_SPLIT 8
#define WLOG_N 393216  // 8*64*64*12

__global__ __launch_bounds__(256) void prep_kernel(
    const float* __restrict__ wconv, const float* __restrict__ gamma,
    const float* __restrict__ beta, const float* __restrict__ mean,
    const float* __restrict__ var, float* __restrict__ wt,
    float* __restrict__ bias, float* __restrict__ gap) {
  const int blk = blockIdx.x;
  const int c = threadIdx.x;  // 0..255
  if (blk < 9) {
    const int t = blk;
    const float sc = gamma[t] * rsqrtf(var[t] + EPS);
    const float* src = wconv + ((size_t)t * 256 + c) * 9;
    float* dst = wt + c * 84;
    #pragma unroll
    for (int ki = 0; ki < 3; ++ki)
      #pragma unroll
      for (int kj = 0; kj < 3; ++kj)
        dst[ki * 28 + t * 3 + kj] = src[ki * 3 + kj] * sc;
  } else {
    #pragma unroll
    for (int ki = 0; ki < 3; ++ki) wt[c * 84 + ki * 28 + 27] = 0.f;
    #pragma unroll
    for (int k = 0; k < 8; ++k) gap[k * 256 + c] = 0.f;
    if (c < 9) bias[c] = beta[c] - mean[c] * gamma[c] * rsqrtf(var[c] + EPS);
    else if (c < 16) bias[c] = 0.f;
  }
}

// Block 256 = 4 waves; block covers channels [z*32, z*32+32) (wave wv owns
// 8), output rows i0..i0+3 of batch b, lanes = 64 output cols.
// Per channel: 9 float2 row loads + 9 scalar left-tap loads (18 independent
// VMEM ops, no shfl on the critical path); 324 FMAs from LDS weights.
// Rows r=1..8 tile the image exactly once -> fused gap sum.
__global__ __launch_bounds__(256, 4) void conv_kernel(
    const float* __restrict__ x, const float* __restrict__ wt,
    float* __restrict__ wlogp, float* __restrict__ gap) {
  const int j = threadIdx.x & 63;
  const int wv = threadIdx.x >> 6;
  const int i0 = blockIdx.x * 4;
  const int b = blockIdx.y;
  const int z = blockIdx.z;

  __shared__ float sw[2688];  // 32 ch * 84
  __shared__ float red[4][64][9];

  {  // cooperative weight stage: channels z*32 .. z*32+31
    const float4* src = (const float4*)(wt + (size_t)z * 32 * 84);
    float4* dst = (float4*)sw;
    #pragma unroll
    for (int k = 0; k < 3; ++k) {
      int idx = k * 256 + threadIdx.x;
      if (idx < 672) dst[idx] = src[idx];
    }
  }
  __syncthreads();

  float acc[4][9];
  #pragma unroll
  for (int ri = 0; ri < 4; ++ri)
    #pragma unroll
    for (int t = 0; t < 9; ++t) acc[ri][t] = 0.f;

  const int cbase = z * 32 + wv * 8;
  const float* xb = x + ((size_t)b * 256 + cbase) * 16384;
  const float* swb = sw + (wv * 8) * 84;
  const int h0 = 2 * i0 - 1;
  const int jl = (j == 0) ? 0 : (2 * j - 1);  // clamped left-tap col

  for (int c = 0; c < 8; ++c) {
    const float* xc = xb + (size_t)c * 16384;
    float2 v[9];
    float lf[9];
    #pragma unroll
    for (int r = 0; r < 9; ++r) {
      const int hh = h0 + r;  // block-uniform; only -1 possible OOB
      if ((unsigned)hh < 128u) {
        v[r] = *(const float2*)(xc + hh * 128 + 2 * j);
        lf[r] = xc[hh * 128 + jl];
      } else {
        v[r] = make_float2(0.f, 0.f);
        lf[r] = 0.f;
      }
    }
    if (j == 0) {
      #pragma unroll
      for (int r = 0; r < 9; ++r) lf[r] = 0.f;  // conv zero-pad col -1
    }

    const float* wcb = swb + c * 84;
    #pragma unroll
    for (int ki = 0; ki < 3; ++ki) {
      float4 wk[7];
      const float4* wq = (const float4*)(wcb + ki * 28);
      #pragma unroll
      for (int q = 0; q < 7; ++q) wk[q] = wq[q];
      const float* w = (const float*)wk;  // w[t*3 + kj]
      #pragma unroll
      for (int ri = 0; ri < 4; ++ri) {
        const int r = 2 * ri + ki;
        const float x0 = lf[r], x1 = v[r].x, x2 = v[r].y;
        #pragma unroll
        for (int t = 0; t < 9; ++t) {
          float a = acc[ri][t];
          a = fmaf(x0, w[t * 3 + 0], a);
          a = fmaf(x1, w[t * 3 + 1], a);
          a = fmaf(x2, w[t * 3 + 2], a);
          acc[ri][t] = a;
        }
      }
    }

    // fused gap: rows r=1..8 owned exactly once across the grid.
    // After the FMA block so the shfl chain overlaps the FMA tail.
    float gs = 0.f;
    #pragma unroll
    for (int r = 1; r < 9; ++r) gs += v[r].x + v[r].y;
    #pragma unroll
    for (int off = 32; off; off >>= 1) gs += __shfl_xor(gs, off, 64);
    if (j == 0) atomicAdd(&gap[b * 256 + cbase + c], gs);
  }

  float* wzp = wlogp + (size_t)z * WLOG_N;
  #pragma unroll
  for (int ri = 0; ri < 4; ++ri) {
    __syncthreads();
    #pragma unroll
    for (int t = 0; t < 9; ++t) red[wv][j][t] = acc[ri][t];
    __syncthreads();
    const size_t rowpos = ((size_t)b * 64 + (i0 + ri)) * 64;
    float* wp = wzp + rowpos * 12;
    for (int idx = threadIdx.x; idx < 768; idx += 256) {
      const int jj = idx / 12, tt = idx - jj * 12;
      float s = 0.f;
      if (tt < 9)
        s = red[0][jj][tt] + red[1][jj][tt] + red[2][jj][tt] + red[3][jj][tt];
      wp[idx] = s;  // coalesced; pad slots get 0
    }
  }
}

// blocks 0..383: wlog[i] = sum_z wlogp[z][i] + bias[i%12]  (float4/thread)
// blocks 384..391: chnet for b = blk-384
__global__ __launch_bounds__(256) void reduce_chnet_kernel(
    const float* __restrict__ wlogp, const float* __restrict__ bias,
    float* __restrict__ wlog, const float* __restrict__ gap,
    const float* __restrict__ w1, const float* __restrict__ w2,
    float* __restrict__ ch) {
  __shared__ float g[256];
  __shared__ float h[64];
  const int blk = blockIdx.x;
  if (blk < 384) {
    const int i4 = blk * 256 + threadIdx.x;  // float4 index
    float4 s = make_float4(0.f, 0.f, 0.f, 0.f);
    #pragma unroll
    for (int zz = 0; zz < 8; ++zz) {
      float4 p = *(const float4*)(wlogp + (size_t)zz * WLOG_N + (size_t)i4 * 4);
      s.x += p.x; s.y += p.y; s.z += p.z; s.w += p.w;
    }
    const int base = i4 * 4;
    s.x += bias[(base + 0) % 12];
    s.y += bias[(base + 1) % 12];
    s.z += bias[(base + 2) % 12];
    s.w += bias[(base + 3) % 12];
    *(float4*)(wlog + base) = s;
  } else {
    const int b = blk - 384;
    const int t = threadIdx.x;
    g[t] = gap[b * 256 + t] * (1.f / 16384.f);
    __syncthreads();
    if (t < 64) {
      float s = 0.f;
      const float* w = w1 + t * 256;
      for (int c = 0; c < 256; ++c) s += g[c] * w[c];
      h[t] = fmaxf(s, 0.f);
    }
    __syncthreads();
    float s = 0.f;
    const float* w = w2 + t * 64;
    #pragma unroll 4
    for (int jj = 0; jj < 64; ++jj) s += h[jj] * w[jj];
    ch[b * 256 + t] = s;
  }
}

// Thread: output cols (2q, 2q+1) of row i, 8 channels. x via float4 (16B/lane);
// left tap from prev lane's .w (shfl width 32); q==0 reflect = own .y.
__global__ __launch_bounds__(256) void final_kernel(
    const float* __restrict__ x, const float* __restrict__ wlog,
    const float* __restrict__ ch, float* __restrict__ out) {
  const int q = threadIdx.x & 31;
  const int rw = threadIdx.x >> 5;   // 0..7
  const int i = blockIdx.x * 8 + rw; // out row
  const int b = blockIdx.y;
  const int c0 = blockIdx.z * 8;

  const size_t pos = ((size_t)b * 64 + i) * 64 + 2 * q;
  const float4* wp = (const float4*)(wlog + pos * 12);
  float4 w0 = wp[0], w1 = wp[1], w2 = wp[2];
  float4 w3 = wp[3], w4 = wp[4], w5 = wp[5];
  const float wlA[9] = {w0.x, w0.y, w0.z, w0.w, w1.x, w1.y, w1.z, w1.w, w2.x};
  const float wlB[9] = {w3.x, w3.y, w3.z, w3.w, w4.x, w4.y, w4.z, w4.w, w5.x};

  float mxA = wlA[0], mnA = wlA[0], mxB = wlB[0], mnB = wlB[0];
  #pragma unroll
  for (int t = 1; t < 9; ++t) {
    mxA = fmaxf(mxA, wlA[t]); mnA = fminf(mnA, wlA[t]);
    mxB = fmaxf(mxB, wlB[t]); mnB = fminf(mnB, wlB[t]);
  }

  const float* chp = ch + b * 256 + c0;
  const float* xp0 = x + ((size_t)b * 256 + c0) * 16384 + 4 * q;
  float* op = out + ((size_t)b * 256 + c0) * 4096 + i * 64 + 2 * q;

  const int hm = (i == 0) ? 1 : 2 * i - 1;  // reflect row -1 -> 1

  for (int c = 0; c < 8; ++c) {
    const float chv = chp[c];
    const float* xp = xp0 + (size_t)c * 16384;
    float4 v0 = *(const float4*)(xp + hm * 128);
    float4 v1 = *(const float4*)(xp + (2 * i) * 128);
    float4 v2 = *(const float4*)(xp + (2 * i + 1) * 128);

    float l0 = __shfl_up(v0.w, 1, 32);
    float l1 = __shfl_up(v1.w, 1, 32);
    float l2 = __shfl_up(v2.w, 1, 32);
    if (q == 0) { l0 = v0.y; l1 = v1.y; l2 = v2.y; }  // reflect col -1 -> 1

    // pixel A: out col 2q, taps {left, .x, .y} per row
    {
      const float m = fmaxf(mxA * chv, mnA * chv);
      float e[9], s = 0.f;
      #pragma unroll
      for (int t = 0; t < 9; ++t) {
        e[t] = __expf(wlA[t] * chv - m);
        s += e[t];
      }
      float acc = e[0] * l0 + e[1] * v0.x + e[2] * v0.y;
      acc += e[3] * l1 + e[4] * v1.x + e[5] * v1.y;
      acc += e[6] * l2 + e[7] * v2.x + e[8] * v2.y;
      op[(size_t)c * 4096] = acc / s;
    }
    // pixel B: out col 2q+1, taps {.y, .z, .w} per row
    {
      const float m = fmaxf(mxB * chv, mnB * chv);
      float e[9], s = 0.f;
      #pragma unroll
      for (int t = 0; t < 9; ++t) {
        e[t] = __expf(wlB[t] * chv - m);
        s += e[t];
      }
      float acc = e[0] * v0.y + e[1] * v0.z + e[2] * v0.w;
      acc += e[3] * v1.y + e[4] * v1.z + e[5] * v1.w;
      acc += e[6] * v2.y + e[7] * v2.z + e[8] * v2.w;
      op[(size_t)c * 4096 + 1] = acc / s;
    }
  }
}

extern "C" void kernel_launch(void* const* d_in, const int* in_sizes, int n_in,
                              void* d_out, int out_size, void* d_ws,
                              size_t ws_size, hipStream_t stream) {
  const float* x = (const float*)d_in[0];
  const float* w_conv = (const float*)d_in[1];
  const float* bn_gamma = (const float*)d_in[2];
  const float* bn_beta = (const float*)d_in[3];
  const float* bn_mean = (const float*)d_in[4];
  const float* bn_var = (const float*)d_in[5];
  const float* ch_w1 = (const float*)d_in[6];
  const float* ch_w2 = (const float*)d_in[7];
  float* out = (float*)d_out;

  float* wsf = (float*)d_ws;
  float* gap = wsf;            // 2048
  float* ch = wsf + 2048;      // 2048
  float* bias = wsf + 4096;    // 16
  float* wt = wsf + 4112;      // 256*84 = 21504
  float* wlog = wsf + 25616;   // 393216
  float* wlogp = wsf + 418832; // 8*393216 = 3145728

  prep_kernel<<<10, 256, 0, stream>>>(w_conv, bn_gamma, bn_beta, bn_mean,
                                      bn_var, wt, bias, gap);
  conv_kernel<<<dim3(16, 8, CH_SPLIT), 256, 0, stream>>>(x, wt, wlogp, gap);
  reduce_chnet_kernel<<<392, 256, 0, stream>>>(wlogp, bias, wlog, gap, ch_w1,
                                               ch_w2, ch);
  final_kernel<<<dim3(8, 8, 32), 256, 0, stream>>>(x, wlog, ch, out);
}

// Round 9
// 79.898 us; speedup vs baseline: 2.0037x; 2.0037x over previous
//
#include <hip/hip_runtime.h>
#include <hip/hip_bf16.h>

// AdaDConv: B=8, C=256, H=W=128, K=3, S=2 -> oh=ow=64, k2=9
//   prep   : fold BN into conv weights -> wt[c][3][28] chunks (10 blocks);
//            bias[16]; gap=0
//   conv   : x -> wlogp[z] partials + fused gap sums. 4-row tile/block,
//            32 ch/block (8/wave), weights staged in LDS, scalar left-tap
//            loads. __launch_bounds__(256,2): the (256,4) variant pinned
//            the allocator to 64 VGPRs and spilled ~320 MB to scratch
//            (rounds 5/7, VGPR=64 + WRITE 259MB). Live set ~100 VGPR needs
//            the 128 cap; occupancy breakpoint at 65..128 still gives
//            4 waves/SIMD.
//   reduce : wlog = sum_z wlogp[z] + bias   (+ chnet in blocks 384..391)
//   final  : column-pair float4 loads; wlog in regs; softmax * reflect -> out

#define EPS 1e-5f
#define CH_SPLIT 8
#define WLOG_N 393216  // 8*64*64*12

__global__ __launch_bounds__(256) void prep_kernel(
    const float* __restrict__ wconv, const float* __restrict__ gamma,
    const float* __restrict__ beta, const float* __restrict__ mean,
    const float* __restrict__ var, float* __restrict__ wt,
    float* __restrict__ bias, float* __restrict__ gap) {
  const int blk = blockIdx.x;
  const int c = threadIdx.x;  // 0..255
  if (blk < 9) {
    const int t = blk;
    const float sc = gamma[t] * rsqrtf(var[t] + EPS);
    const float* src = wconv + ((size_t)t * 256 + c) * 9;
    float* dst = wt + c * 84;
    #pragma unroll
    for (int ki = 0; ki < 3; ++ki)
      #pragma unroll
      for (int kj = 0; kj < 3; ++kj)
        dst[ki * 28 + t * 3 + kj] = src[ki * 3 + kj] * sc;
  } else {
    #pragma unroll
    for (int ki = 0; ki < 3; ++ki) wt[c * 84 + ki * 28 + 27] = 0.f;
    #pragma unroll
    for (int k = 0; k < 8; ++k) gap[k * 256 + c] = 0.f;
    if (c < 9) bias[c] = beta[c] - mean[c] * gamma[c] * rsqrtf(var[c] + EPS);
    else if (c < 16) bias[c] = 0.f;
  }
}

// Block 256 = 4 waves; block covers channels [z*32, z*32+32) (wave wv owns
// 8), output rows i0..i0+3 of batch b, lanes = 64 output cols.
// Per channel: 9 float2 row loads + 9 scalar left-tap loads (independent
// VMEM, no shfl on the critical path); 324 FMAs from LDS weights.
// Rows r=1..8 tile the image exactly once -> fused gap sum.
__global__ __launch_bounds__(256, 2) void conv_kernel(
    const float* __restrict__ x, const float* __restrict__ wt,
    float* __restrict__ wlogp, float* __restrict__ gap) {
  const int j = threadIdx.x & 63;
  const int wv = threadIdx.x >> 6;
  const int i0 = blockIdx.x * 4;
  const int b = blockIdx.y;
  const int z = blockIdx.z;

  __shared__ float sw[2688];  // 32 ch * 84
  __shared__ float red[4][64][9];

  {  // cooperative weight stage: channels z*32 .. z*32+31
    const float4* src = (const float4*)(wt + (size_t)z * 32 * 84);
    float4* dst = (float4*)sw;
    #pragma unroll
    for (int k = 0; k < 3; ++k) {
      int idx = k * 256 + threadIdx.x;
      if (idx < 672) dst[idx] = src[idx];
    }
  }
  __syncthreads();

  float acc[4][9];
  #pragma unroll
  for (int ri = 0; ri < 4; ++ri)
    #pragma unroll
    for (int t = 0; t < 9; ++t) acc[ri][t] = 0.f;

  const int cbase = z * 32 + wv * 8;
  const float* xb = x + ((size_t)b * 256 + cbase) * 16384;
  const float* swb = sw + (wv * 8) * 84;
  const int h0 = 2 * i0 - 1;
  const int jl = (j == 0) ? 0 : (2 * j - 1);  // clamped left-tap col

  for (int c = 0; c < 8; ++c) {
    const float* xc = xb + (size_t)c * 16384;
    float2 v[9];
    float lf[9];
    #pragma unroll
    for (int r = 0; r < 9; ++r) {
      const int hh = h0 + r;  // block-uniform; only -1 possible OOB
      if ((unsigned)hh < 128u) {
        v[r] = *(const float2*)(xc + hh * 128 + 2 * j);
        lf[r] = xc[hh * 128 + jl];
      } else {
        v[r] = make_float2(0.f, 0.f);
        lf[r] = 0.f;
      }
    }
    if (j == 0) {
      #pragma unroll
      for (int r = 0; r < 9; ++r) lf[r] = 0.f;  // conv zero-pad col -1
    }

    // fused gap first (shortens v[] liveness): rows r=1..8 owned once
    {
      float gs = 0.f;
      #pragma unroll
      for (int r = 1; r < 9; ++r) gs += v[r].x + v[r].y;
      #pragma unroll
      for (int off = 32; off; off >>= 1) gs += __shfl_xor(gs, off, 64);
      if (j == 0) atomicAdd(&gap[b * 256 + cbase + c], gs);
    }

    const float* wcb = swb + c * 84;
    #pragma unroll
    for (int ki = 0; ki < 3; ++ki) {
      float4 wk[7];
      const float4* wq = (const float4*)(wcb + ki * 28);
      #pragma unroll
      for (int q = 0; q < 7; ++q) wk[q] = wq[q];
      const float* w = (const float*)wk;  // w[t*3 + kj]
      #pragma unroll
      for (int ri = 0; ri < 4; ++ri) {
        const int r = 2 * ri + ki;
        const float x0 = lf[r], x1 = v[r].x, x2 = v[r].y;
        #pragma unroll
        for (int t = 0; t < 9; ++t) {
          float a = acc[ri][t];
          a = fmaf(x0, w[t * 3 + 0], a);
          a = fmaf(x1, w[t * 3 + 1], a);
          a = fmaf(x2, w[t * 3 + 2], a);
          acc[ri][t] = a;
        }
      }
    }
  }

  float* wzp = wlogp + (size_t)z * WLOG_N;
  #pragma unroll
  for (int ri = 0; ri < 4; ++ri) {
    __syncthreads();
    #pragma unroll
    for (int t = 0; t < 9; ++t) red[wv][j][t] = acc[ri][t];
    __syncthreads();
    const size_t rowpos = ((size_t)b * 64 + (i0 + ri)) * 64;
    float* wp = wzp + rowpos * 12;
    for (int idx = threadIdx.x; idx < 768; idx += 256) {
      const int jj = idx / 12, tt = idx - jj * 12;
      float s = 0.f;
      if (tt < 9)
        s = red[0][jj][tt] + red[1][jj][tt] + red[2][jj][tt] + red[3][jj][tt];
      wp[idx] = s;  // coalesced; pad slots get 0
    }
  }
}

// blocks 0..383: wlog[i] = sum_z wlogp[z][i] + bias[i%12]  (float4/thread)
// blocks 384..391: chnet for b = blk-384
__global__ __launch_bounds__(256) void reduce_chnet_kernel(
    const float* __restrict__ wlogp, const float* __restrict__ bias,
    float* __restrict__ wlog, const float* __restrict__ gap,
    const float* __restrict__ w1, const float* __restrict__ w2,
    float* __restrict__ ch) {
  __shared__ float g[256];
  __shared__ float h[64];
  const int blk = blockIdx.x;
  if (blk < 384) {
    const int i4 = blk * 256 + threadIdx.x;  // float4 index
    float4 s = make_float4(0.f, 0.f, 0.f, 0.f);
    #pragma unroll
    for (int zz = 0; zz < 8; ++zz) {
      float4 p = *(const float4*)(wlogp + (size_t)zz * WLOG_N + (size_t)i4 * 4);
      s.x += p.x; s.y += p.y; s.z += p.z; s.w += p.w;
    }
    const int base = i4 * 4;
    s.x += bias[(base + 0) % 12];
    s.y += bias[(base + 1) % 12];
    s.z += bias[(base + 2) % 12];
    s.w += bias[(base + 3) % 12];
    *(float4*)(wlog + base) = s;
  } else {
    const int b = blk - 384;
    const int t = threadIdx.x;
    g[t] = gap[b * 256 + t] * (1.f / 16384.f);
    __syncthreads();
    if (t < 64) {
      float s = 0.f;
      const float* w = w1 + t * 256;
      for (int c = 0; c < 256; ++c) s += g[c] * w[c];
      h[t] = fmaxf(s, 0.f);
    }
    __syncthreads();
    float s = 0.f;
    const float* w = w2 + t * 64;
    #pragma unroll 4
    for (int jj = 0; jj < 64; ++jj) s += h[jj] * w[jj];
    ch[b * 256 + t] = s;
  }
}

// Thread: output cols (2q, 2q+1) of row i, 8 channels. x via float4 (16B/lane);
// left tap from prev lane's .w (shfl width 32); q==0 reflect = own .y.
__global__ __launch_bounds__(256) void final_kernel(
    const float* __restrict__ x, const float* __restrict__ wlog,
    const float* __restrict__ ch, float* __restrict__ out) {
  const int q = threadIdx.x & 31;
  const int rw = threadIdx.x >> 5;   // 0..7
  const int i = blockIdx.x * 8 + rw; // out row
  const int b = blockIdx.y;
  const int c0 = blockIdx.z * 8;

  const size_t pos = ((size_t)b * 64 + i) * 64 + 2 * q;
  const float4* wp = (const float4*)(wlog + pos * 12);
  float4 w0 = wp[0], w1 = wp[1], w2 = wp[2];
  float4 w3 = wp[3], w4 = wp[4], w5 = wp[5];
  const float wlA[9] = {w0.x, w0.y, w0.z, w0.w, w1.x, w1.y, w1.z, w1.w, w2.x};
  const float wlB[9] = {w3.x, w3.y, w3.z, w3.w, w4.x, w4.y, w4.z, w4.w, w5.x};

  float mxA = wlA[0], mnA = wlA[0], mxB = wlB[0], mnB = wlB[0];
  #pragma unroll
  for (int t = 1; t < 9; ++t) {
    mxA = fmaxf(mxA, wlA[t]); mnA = fminf(mnA, wlA[t]);
    mxB = fmaxf(mxB, wlB[t]); mnB = fminf(mnB, wlB[t]);
  }

  const float* chp = ch + b * 256 + c0;
  const float* xp0 = x + ((size_t)b * 256 + c0) * 16384 + 4 * q;
  float* op = out + ((size_t)b * 256 + c0) * 4096 + i * 64 + 2 * q;

  const int hm = (i == 0) ? 1 : 2 * i - 1;  // reflect row -1 -> 1

  for (int c = 0; c < 8; ++c) {
    const float chv = chp[c];
    const float* xp = xp0 + (size_t)c * 16384;
    float4 v0 = *(const float4*)(xp + hm * 128);
    float4 v1 = *(const float4*)(xp + (2 * i) * 128);
    float4 v2 = *(const float4*)(xp + (2 * i + 1) * 128);

    float l0 = __shfl_up(v0.w, 1, 32);
    float l1 = __shfl_up(v1.w, 1, 32);
    float l2 = __shfl_up(v2.w, 1, 32);
    if (q == 0) { l0 = v0.y; l1 = v1.y; l2 = v2.y; }  // reflect col -1 -> 1

    // pixel A: out col 2q, taps {left, .x, .y} per row
    {
      const float m = fmaxf(mxA * chv, mnA * chv);
      float e[9], s = 0.f;
      #pragma unroll
      for (int t = 0; t < 9; ++t) {
        e[t] = __expf(wlA[t] * chv - m);
        s += e[t];
      }
      float acc = e[0] * l0 + e[1] * v0.x + e[2] * v0.y;
      acc += e[3] * l1 + e[4] * v1.x + e[5] * v1.y;
      acc += e[6] * l2 + e[7] * v2.x + e[8] * v2.y;
      op[(size_t)c * 4096] = acc / s;
    }
    // pixel B: out col 2q+1, taps {.y, .z, .w} per row
    {
      const float m = fmaxf(mxB * chv, mnB * chv);
      float e[9], s = 0.f;
      #pragma unroll
      for (int t = 0; t < 9; ++t) {
        e[t] = __expf(wlB[t] * chv - m);
        s += e[t];
      }
      float acc = e[0] * v0.y + e[1] * v0.z + e[2] * v0.w;
      acc += e[3] * v1.y + e[4] * v1.z + e[5] * v1.w;
      acc += e[6] * v2.y + e[7] * v2.z + e[8] * v2.w;
      op[(size_t)c * 4096 + 1] = acc / s;
    }
  }
}

extern "C" void kernel_launch(void* const* d_in, const int* in_sizes, int n_in,
                              void* d_out, int out_size, void* d_ws,
                              size_t ws_size, hipStream_t stream) {
  const float* x = (const float*)d_in[0];
  const float* w_conv = (const float*)d_in[1];
  const float* bn_gamma = (const float*)d_in[2];
  const float* bn_beta = (const float*)d_in[3];
  const float* bn_mean = (const float*)d_in[4];
  const float* bn_var = (const float*)d_in[5];
  const float* ch_w1 = (const float*)d_in[6];
  const float* ch_w2 = (const float*)d_in[7];
  float* out = (float*)d_out;

  float* wsf = (float*)d_ws;
  float* gap = wsf;            // 2048
  float* ch = wsf + 2048;      // 2048
  float* bias = wsf + 4096;    // 16
  float* wt = wsf + 4112;      // 256*84 = 21504
  float* wlog = wsf + 25616;   // 393216
  float* wlogp = wsf + 418832; // 8*393216 = 3145728

  prep_kernel<<<10, 256, 0, stream>>>(w_conv, bn_gamma, bn_beta, bn_mean,
                                      bn_var, wt, bias, gap);
  conv_kernel<<<dim3(16, 8, CH_SPLIT), 256, 0, stream>>>(x, wt, wlogp, gap);
  reduce_chnet_kernel<<<392, 256, 0, stream>>>(wlogp, bias, wlog, gap, ch_w1,
                                               ch_w2, ch);
  final_kernel<<<dim3(8, 8, 32), 256, 0, stream>>>(x, wlog, ch, out);
}